// Round 1
// baseline (140.574 us; speedup 1.0000x reference)
//
#include <hip/hip_runtime.h>
#include <hip/hip_bf16.h>
#include <math.h>

#define D_DIM 192
#define H_DIM 224
#define W_DIM 192

// ---------------------------------------------------------------------------
// Kernel 1: compose the 4x4 transform on-device (single thread).
// T = inv(flo_v2r) @ (T_center_inv @ T_trans @ T_rot @ T_sc @ T_center) @ ref_v2r
// Writes rows 0..2 (12 floats) of T to Tout.
// ---------------------------------------------------------------------------

__device__ inline void mm4(const float* A, const float* B, float* C) {
    for (int r = 0; r < 4; ++r)
        for (int c = 0; c < 4; ++c) {
            float s = 0.f;
            for (int t = 0; t < 4; ++t) s += A[r * 4 + t] * B[t * 4 + c];
            C[r * 4 + c] = s;
        }
}

__device__ inline void inv4(const float* Ain, float* out) {
    // Gauss-Jordan with partial pivoting on [A | I]
    float a[4][8];
    for (int r = 0; r < 4; ++r) {
        for (int c = 0; c < 4; ++c) a[r][c] = Ain[r * 4 + c];
        for (int c = 0; c < 4; ++c) a[r][4 + c] = (r == c) ? 1.f : 0.f;
    }
    for (int col = 0; col < 4; ++col) {
        int piv = col;
        float best = fabsf(a[col][col]);
        for (int r = col + 1; r < 4; ++r) {
            float v = fabsf(a[r][col]);
            if (v > best) { best = v; piv = r; }
        }
        if (piv != col) {
            for (int c = 0; c < 8; ++c) {
                float t = a[col][c]; a[col][c] = a[piv][c]; a[piv][c] = t;
            }
        }
        float inv = 1.f / a[col][col];
        for (int c = 0; c < 8; ++c) a[col][c] *= inv;
        for (int r = 0; r < 4; ++r) {
            if (r == col) continue;
            float f = a[r][col];
            for (int c = 0; c < 8; ++c) a[r][c] -= f * a[col][c];
        }
    }
    for (int r = 0; r < 4; ++r)
        for (int c = 0; c < 4; ++c) out[r * 4 + c] = a[r][4 + c];
}

__global__ void compute_T_kernel(const float* __restrict__ ang,
                                 const float* __restrict__ tr,
                                 const float* __restrict__ scl,
                                 const float* __restrict__ ref_v2r,
                                 const float* __restrict__ flo_v2r,
                                 float* __restrict__ Tout) {
    if (threadIdx.x != 0 || blockIdx.x != 0) return;

    const float cogx = 96.f, cogy = 112.f, cogz = 96.f;

    float cx = cosf(ang[0]), sx = sinf(ang[0]);
    float cy = cosf(ang[1]), sy = sinf(ang[1]);
    float cz = cosf(ang[2]), sz = sinf(ang[2]);

    // R = Rx @ Ry @ Rz
    float Rx[9] = {1, 0, 0, 0, cx, -sx, 0, sx, cx};
    float Ry[9] = {cy, 0, sy, 0, 1, 0, -sy, 0, cy};
    float Rz[9] = {cz, -sz, 0, sz, cz, 0, 0, 0, 1};
    float Ryz[9], R[9];
    for (int r = 0; r < 3; ++r)
        for (int c = 0; c < 3; ++c) {
            float s = 0.f;
            for (int t = 0; t < 3; ++t) s += Ry[r * 3 + t] * Rz[t * 3 + c];
            Ryz[r * 3 + c] = s;
        }
    for (int r = 0; r < 3; ++r)
        for (int c = 0; c < 3; ++c) {
            float s = 0.f;
            for (int t = 0; t < 3; ++t) s += Rx[r * 3 + t] * Ryz[t * 3 + c];
            R[r * 3 + c] = s;
        }

    float s0 = expf(scl[0]), s1 = expf(scl[1]), s2 = expf(scl[2]);

    float Tc[16]    = {1,0,0,-cogx, 0,1,0,-cogy, 0,0,1,-cogz, 0,0,0,1};
    float Tci[16]   = {1,0,0, cogx, 0,1,0, cogy, 0,0,1, cogz, 0,0,0,1};
    float Tsc[16]   = {s0,0,0,0, 0,s1,0,0, 0,0,s2,0, 0,0,0,1};
    float Ttr[16]   = {1,0,0,tr[0], 0,1,0,tr[1], 0,0,1,tr[2], 0,0,0,1};
    float Trot[16]  = {R[0],R[1],R[2],0, R[3],R[4],R[5],0, R[6],R[7],R[8],0, 0,0,0,1};

    // T_rig = Tci @ Ttr @ Trot @ Tsc @ Tc
    float m1[16], m2[16], m3[16], Trig[16];
    mm4(Tci, Ttr, m1);
    mm4(m1, Trot, m2);
    mm4(m2, Tsc, m3);
    mm4(m3, Tc, Trig);

    float floinv[16], m4[16], T[16];
    inv4(flo_v2r, floinv);
    mm4(floinv, Trig, m4);
    mm4(m4, ref_v2r, T);

    for (int q = 0; q < 12; ++q) Tout[q] = T[q];
}

// ---------------------------------------------------------------------------
// Kernel 2: trilinear resample. One thread per voxel; block covers one W-row.
// ---------------------------------------------------------------------------

__global__ __launch_bounds__(W_DIM) void resample_kernel(
    const float* __restrict__ vol,
    const float* __restrict__ T,
    float* __restrict__ out) {
    const int k = threadIdx.x;       // 0..191 (W)
    const int j = blockIdx.y;        // 0..223 (H)
    const int i = blockIdx.z;        // 0..191 (D)

    const float fi = (float)i, fj = (float)j, fk = (float)k;

    const float t00 = T[0],  t01 = T[1],  t02 = T[2],  t03 = T[3];
    const float t10 = T[4],  t11 = T[5],  t12 = T[6],  t13 = T[7];
    const float t20 = T[8],  t21 = T[9],  t22 = T[10], t23 = T[11];

    const float di = t00 * fi + t01 * fj + t02 * fk + t03;
    const float dj = t10 * fi + t11 * fj + t12 * fk + t13;
    const float dk = t20 * fi + t21 * fj + t22 * fk + t23;

    const bool ok = (di > 0.f) & (dj > 0.f) & (dk > 0.f) &
                    (di <= (float)(D_DIM - 1)) &
                    (dj <= (float)(H_DIM - 1)) &
                    (dk <= (float)(W_DIM - 1));

    // floor, clipped to [0, dim-1] (matches reference; only matters when !ok)
    float ffi = fminf(fmaxf(floorf(di), 0.f), (float)(D_DIM - 1));
    float ffj = fminf(fmaxf(floorf(dj), 0.f), (float)(H_DIM - 1));
    float ffk = fminf(fmaxf(floorf(dk), 0.f), (float)(W_DIM - 1));

    const float wi = di - ffi;
    const float wj = dj - ffj;
    const float wk = dk - ffk;

    const int i0 = (int)ffi, j0 = (int)ffj, k0 = (int)ffk;
    const int i1 = min(i0 + 1, D_DIM - 1);
    const int j1 = min(j0 + 1, H_DIM - 1);
    const int k1 = min(k0 + 1, W_DIM - 1);

    const int base00 = (i0 * H_DIM + j0) * W_DIM;  // i0,j0
    const int base01 = (i0 * H_DIM + j1) * W_DIM;  // i0,j1
    const int base10 = (i1 * H_DIM + j0) * W_DIM;  // i1,j0
    const int base11 = (i1 * H_DIM + j1) * W_DIM;  // i1,j1

    const float c000 = vol[base00 + k0];
    const float c100 = vol[base10 + k0];
    const float c010 = vol[base01 + k0];
    const float c110 = vol[base11 + k0];
    const float c001 = vol[base00 + k1];
    const float c101 = vol[base10 + k1];
    const float c011 = vol[base01 + k1];
    const float c111 = vol[base11 + k1];

    const float omwi = 1.f - wi, omwj = 1.f - wj, omwk = 1.f - wk;

    const float v = ((c000 * omwi + c100 * wi) * omwj +
                     (c010 * omwi + c110 * wi) * wj) * omwk +
                    ((c001 * omwi + c101 * wi) * omwj +
                     (c011 * omwi + c111 * wi) * wj) * wk;

    out[(i * H_DIM + j) * W_DIM + k] = ok ? v : 0.f;
}

// ---------------------------------------------------------------------------

extern "C" void kernel_launch(void* const* d_in, const int* in_sizes, int n_in,
                              void* d_out, int out_size, void* d_ws, size_t ws_size,
                              hipStream_t stream) {
    const float* image_targ  = (const float*)d_in[0];  // (1,1,192,224,192)
    const float* angle       = (const float*)d_in[1];  // (1,3)
    const float* translation = (const float*)d_in[2];  // (1,3)
    const float* scaling     = (const float*)d_in[3];  // (1,3)
    const float* ref_v2r     = (const float*)d_in[4];  // (4,4)
    const float* flo_v2r     = (const float*)d_in[5];  // (4,4)
    float* out = (float*)d_out;
    float* Tmat = (float*)d_ws;  // 12 floats

    compute_T_kernel<<<1, 1, 0, stream>>>(angle, translation, scaling,
                                          ref_v2r, flo_v2r, Tmat);

    dim3 block(W_DIM, 1, 1);
    dim3 grid(1, H_DIM, D_DIM);
    resample_kernel<<<grid, block, 0, stream>>>(image_targ, Tmat, out);
}